// Round 5
// baseline (404.277 us; speedup 1.0000x reference)
//
#include <hip/hip_runtime.h>
#include <math.h>

#define N 512
#define CS 384
#define CZ 128
#define NH 16
#define DH 24
#define HD 384
#define NN (N*N)
#define EPS 1e-5f

// ws layout (float offsets)
#define OFF_AN   0          // a_n [N][CS]
#define OFF_QT   196608     // qT [H][N][D] (pre-scaled by 1/sqrt(24))
#define OFF_KT   393216     // kT [H][N][D]
#define OFF_VT   589824     // vT [H][N][D]
#define OFF_GT   786432     // gT [H][N][D] (sigmoid applied)
#define OFF_OG   983040     // o*g [N][HD]
#define OFF_WZ2  1179648    // g_z*Wz transposed [H][CZ]
#define OFF_SH   1181696    // [H]
#define OFF_BH   1181712    // [H]
#define OFF_BIAS 1181728    // pair bias [H][N][N]

// ---------------- fused: prep (block 256) + LayerNorm of a (blocks 0..255, 2 rows each) ----------------
__global__ void __launch_bounds__(256) ln_prep_kernel(const float* __restrict__ a, const float* __restrict__ g_a,
                                                      const float* __restrict__ b_a, float* __restrict__ an_out,
                                                      const float* __restrict__ g_z, const float* __restrict__ lnb_z,
                                                      const float* __restrict__ Wz, const float* __restrict__ bz,
                                                      float* __restrict__ wz2, float* __restrict__ sh,
                                                      float* __restrict__ bh) {
    __shared__ float ls[NH][17], lb[NH][17];   // prep block
    __shared__ float l1[4], l2[4];             // ln blocks
    const int t = threadIdx.x;
    if (blockIdx.x == 256) {
        // prep: Wz2[h][c] = g_z[c]*Wz[c][h]; Sh, Bh
        for (int i = t; i < NH * CZ; i += 256) {
            int h = i >> 7, c = i & (CZ - 1);
            wz2[h * CZ + c] = g_z[c] * Wz[c * NH + h];
        }
        int h = t >> 4, seg = t & 15;
        float s = 0.f, b = 0.f;
        #pragma unroll
        for (int i = 0; i < 8; ++i) {
            int c = seg * 8 + i;
            float w = Wz[c * NH + h];
            s += g_z[c] * w;
            b += lnb_z[c] * w;
        }
        ls[h][seg] = s; lb[h][seg] = b;
        __syncthreads();
        if (t < NH) {
            float ss = 0.f, bb = 0.f;
            #pragma unroll
            for (int i = 0; i < 16; ++i) { ss += ls[t][i]; bb += lb[t][i]; }
            sh[t] = ss;
            bh[t] = bb + bz[t];
        }
        return;
    }
    // LayerNorm: 2 rows per block (threads 0..127 -> row0, 128..255 -> row1)
    const int half = t >> 7;
    const int tr = t & 127;
    const int r = blockIdx.x * 2 + half;
    const float* row = a + r * CS;
    float x0 = row[tr], x1 = row[tr + 128], x2 = row[tr + 256];
    float s1 = x0 + x1 + x2;
    float s2 = x0 * x0 + x1 * x1 + x2 * x2;
    #pragma unroll
    for (int m = 1; m < 64; m <<= 1) {
        s1 += __shfl_xor(s1, m, 64);
        s2 += __shfl_xor(s2, m, 64);
    }
    if ((t & 63) == 0) { l1[t >> 6] = s1; l2[t >> 6] = s2; }
    __syncthreads();
    s1 = l1[half * 2] + l1[half * 2 + 1];
    s2 = l2[half * 2] + l2[half * 2 + 1];
    float mu = s1 * (1.f / CS);
    float var = s2 * (1.f / CS) - mu * mu;
    float rs = rsqrtf(var + EPS);
    float* an = an_out + r * CS;
    an[tr]       = (x0 - mu) * rs * g_a[tr]       + b_a[tr];
    an[tr + 128] = (x1 - mu) * rs * g_a[tr + 128] + b_a[tr + 128];
    an[tr + 256] = (x2 - mu) * rs * g_a[tr + 256] + b_a[tr + 256];
}

// ---------------- fused qp2: pairbias (4096 blocks) + qkvg (512 blocks), INTERLEAVED mod 9 ----------------
// Role: blockIdx%9==8 -> qkvg block bq=blockIdx/9 (0..511); else pairbias pb=blockIdx-(blockIdx+1)/9 (0..4095).
// Interleaving keeps memory-stalled pairbias waves and VALU/s_load-bound qkvg waves co-resident
// on every CU for the whole kernel (round-1 failure mode was contiguous role ranges = sequential).
// pairbias: 64-row tile, 4 threads/row, cheap-XOR LDS (round-4 v4, proven).
// qkvg: 6 cols/thread, 2048 waves; wid=bq*4+w, strip=wid>>3 (0..255), mb=wid&7.
__global__ void __launch_bounds__(256, 4) qp2_kernel(const float* __restrict__ z,
                                                     const float* __restrict__ wz2,
                                                     const float* __restrict__ sh,
                                                     const float* __restrict__ bh,
                                                     float* __restrict__ bias,
                                                     const float* __restrict__ Wq, const float* __restrict__ Wk,
                                                     const float* __restrict__ Wv, const float* __restrict__ Wg,
                                                     const float* __restrict__ bg, const float* __restrict__ an,
                                                     float* __restrict__ qt, float* __restrict__ kt,
                                                     float* __restrict__ vt, float* __restrict__ gt) {
    __shared__ float4 lz[64 * 32];   // 32 KB (charged to both roles; 4 blocks/CU either way)
    const int b = blockIdx.x;
    const int t = threadIdx.x;
    const int lane = t & 63;
    const int w = __builtin_amdgcn_readfirstlane(t >> 6);
    if (b % 9 == 8) {
        // ---- qkvg role: 6 cols/thread ----
        const int bq = b / 9;                 // 0..511
        const int wid = bq * 4 + w;           // 0..2047
        const int strip = wid >> 3;           // 0..255
        const int mb = wid & 7;
        const int n0 = strip * 6;             // multiple of 6; 384%6==0 -> never straddles a matrix
        const int sel = n0 / HD;              // 0:q 1:k 2:v 3:g
        const int col = n0 - sel * HD;
        const float* Wm = (sel == 0) ? Wq : (sel == 1) ? Wk : (sel == 2) ? Wv : Wg;
        const int m = mb * 64 + lane;
        const float* arow = an + m * CS;
        float acc[6];
        #pragma unroll
        for (int j = 0; j < 6; ++j) acc[j] = 0.f;
        for (int kb = 0; kb < CS; kb += 32) {
            float4 av[8];
            #pragma unroll
            for (int i = 0; i < 8; ++i) av[i] = ((const float4*)(arow + kb))[i]; // full 128B line
            #pragma unroll
            for (int i = 0; i < 8; ++i) {
                const float* wr = Wm + (kb + i * 4) * HD + col; // wave-uniform -> s_load
                #pragma unroll
                for (int j = 0; j < 6; ++j) {
                    acc[j] += av[i].x * wr[j];
                    acc[j] += av[i].y * wr[HD + j];
                    acc[j] += av[i].z * wr[2 * HD + j];
                    acc[j] += av[i].w * wr[3 * HD + j];
                }
            }
        }
        float* dst = (sel == 0) ? qt : (sel == 1) ? kt : (sel == 2) ? vt : gt;
        if (sel == 3) {
            #pragma unroll
            for (int j = 0; j < 6; ++j) acc[j] = 1.f / (1.f + __expf(-(acc[j] + bg[col + j])));
        } else if (sel == 0) {
            #pragma unroll
            for (int j = 0; j < 6; ++j) acc[j] *= 0.20412414523193153f; // 1/sqrt(24)
        }
        // 24%6==0 -> all 6 cols in the same head
        const int h = col / DH, d0 = col - h * DH;
        float* dp = dst + (h * N + m) * DH + d0;
        #pragma unroll
        for (int j = 0; j < 6; ++j) dp[j] = acc[j];
        return;
    }
    // ---- pairbias role (round-4 v4) ----
    const int pb = b - (b + 1) / 9;           // 0..4095
    const int l = t & 63;                     // row within tile
    const int h0 = w * 4;                     // head group (wave-uniform)
    const int row0 = pb * 64;

    // stage: 64 rows x 32 float4 = 2048 float4; 8 per thread, contiguous per wave-instr
    const float4* zsrc = (const float4*)(z + (size_t)row0 * CZ);
    #pragma unroll
    for (int i = 0; i < 8; ++i) {
        const int g4 = i * 256 + t;            // 0..2047
        float4 v = zsrc[g4];
        const int r = g4 >> 5, cc = g4 & 31;
        lz[r * 32 + (cc ^ (r & 31))] = v;
    }
    __syncthreads();

    const unsigned base = (unsigned)(l * 512 + ((l & 31) << 4));  // byte offset of row l, slot (l&31)
    const char* lzb = (const char*)lz;
    float s1 = 0.f, s2 = 0.f;
    float dots[4];
    #pragma unroll
    for (int j = 0; j < 4; ++j) dots[j] = 0.f;
    #pragma unroll
    for (int cc = 0; cc < 32; ++cc) {
        float4 v = *(const float4*)(lzb + (base ^ (unsigned)(cc << 4)));
        s1 += v.x + v.y + v.z + v.w;
        s2 += v.x * v.x + v.y * v.y + v.z * v.z + v.w * v.w;
        #pragma unroll
        for (int j = 0; j < 4; ++j) {
            const float4 wv = ((const float4*)(wz2 + (h0 + j) * CZ))[cc]; // wave-uniform -> s_load
            dots[j] += v.x * wv.x + v.y * wv.y + v.z * wv.z + v.w * wv.w;
        }
    }
    const float mu = s1 * (1.f / CZ);
    const float var = s2 * (1.f / CZ) - mu * mu;
    const float rr = rsqrtf(var + EPS);
    const int row = row0 + l;
    #pragma unroll
    for (int j = 0; j < 4; ++j)
        bias[(h0 + j) * NN + row] = rr * (dots[j] - mu * sh[h0 + j]) + bh[h0 + j];
}

// ---------------- attention: 2 q per wave, 32 lanes per q over k. 4096 waves ----------------
__global__ void __launch_bounds__(256) attn_kernel(const float* __restrict__ qt, const float* __restrict__ kt,
                                                   const float* __restrict__ vt, const float* __restrict__ gt,
                                                   const float* __restrict__ bias, float* __restrict__ og) {
    const int lane = threadIdx.x & 63;
    const int w = __builtin_amdgcn_readfirstlane(threadIdx.x >> 6);
    const int qhalf = lane >> 5;     // 0/1
    const int klane = lane & 31;
    const int h = blockIdx.y;
    const int q = blockIdx.x * 8 + w * 2 + qhalf;
    const float* qT = qt + h * N * DH;
    const float* kT = kt + h * N * DH;
    const float* vT = vt + h * N * DH;

    float qv[DH];
    #pragma unroll
    for (int d6 = 0; d6 < 6; ++d6) {
        float4 t4 = ((const float4*)(qT + q * DH))[d6];
        qv[d6 * 4 + 0] = t4.x; qv[d6 * 4 + 1] = t4.y; qv[d6 * 4 + 2] = t4.z; qv[d6 * 4 + 3] = t4.w;
    }
    float sc[16];
    #pragma unroll
    for (int t = 0; t < 16; ++t) {
        const int kk = t * 32 + klane;
        const float4* kr = (const float4*)(kT + kk * DH);
        float4 k0 = kr[0], k1 = kr[1], k2 = kr[2], k3 = kr[3], k4 = kr[4], k5 = kr[5];
        float s = qv[0]*k0.x + qv[1]*k0.y + qv[2]*k0.z + qv[3]*k0.w
                + qv[4]*k1.x + qv[5]*k1.y + qv[6]*k1.z + qv[7]*k1.w
                + qv[8]*k2.x + qv[9]*k2.y + qv[10]*k2.z + qv[11]*k2.w
                + qv[12]*k3.x + qv[13]*k3.y + qv[14]*k3.z + qv[15]*k3.w
                + qv[16]*k4.x + qv[17]*k4.y + qv[18]*k4.z + qv[19]*k4.w
                + qv[20]*k5.x + qv[21]*k5.y + qv[22]*k5.z + qv[23]*k5.w;
        sc[t] = s + bias[h * NN + q * N + kk];
    }
    float mx = sc[0];
    #pragma unroll
    for (int t = 1; t < 16; ++t) mx = fmaxf(mx, sc[t]);
    #pragma unroll
    for (int m = 1; m < 32; m <<= 1) mx = fmaxf(mx, __shfl_xor(mx, m, 64));
    float sum = 0.f;
    #pragma unroll
    for (int t = 0; t < 16; ++t) { sc[t] = __expf(sc[t] - mx); sum += sc[t]; }
    #pragma unroll
    for (int m = 1; m < 32; m <<= 1) sum += __shfl_xor(sum, m, 64);
    float inv = 1.f / sum;
    #pragma unroll
    for (int t = 0; t < 16; ++t) sc[t] *= inv;
    float acc[DH];
    #pragma unroll
    for (int d = 0; d < DH; ++d) acc[d] = 0.f;
    #pragma unroll
    for (int t = 0; t < 16; ++t) {
        const int kk = t * 32 + klane;
        const float4* vr = (const float4*)(vT + kk * DH);
        float4 v0 = vr[0], v1 = vr[1], v2 = vr[2], v3 = vr[3], v4 = vr[4], v5 = vr[5];
        float p = sc[t];
        acc[0] += p*v0.x;  acc[1] += p*v0.y;  acc[2] += p*v0.z;  acc[3] += p*v0.w;
        acc[4] += p*v1.x;  acc[5] += p*v1.y;  acc[6] += p*v1.z;  acc[7] += p*v1.w;
        acc[8] += p*v2.x;  acc[9] += p*v2.y;  acc[10] += p*v2.z; acc[11] += p*v2.w;
        acc[12] += p*v3.x; acc[13] += p*v3.y; acc[14] += p*v3.z; acc[15] += p*v3.w;
        acc[16] += p*v4.x; acc[17] += p*v4.y; acc[18] += p*v4.z; acc[19] += p*v4.w;
        acc[20] += p*v5.x; acc[21] += p*v5.y; acc[22] += p*v5.z; acc[23] += p*v5.w;
    }
    #pragma unroll
    for (int m = 1; m < 32; m <<= 1) {
        #pragma unroll
        for (int d = 0; d < DH; ++d) acc[d] += __shfl_xor(acc[d], m, 64);
    }
    float o = 0.f;
    #pragma unroll
    for (int d = 0; d < DH; ++d) o = (klane == d) ? acc[d] : o;
    if (klane < DH) {
        float g = gt[h * N * DH + q * DH + klane];
        og[q * HD + h * DH + klane] = o * g;
    }
}

// ---------------- out = og @ Wo + bo (2 cols/thread, 1536 waves — 2x occupancy) ----------------
__global__ void __launch_bounds__(256) out_gemm_kernel(const float* __restrict__ Wo, const float* __restrict__ bo,
                                                       const float* __restrict__ og, float* __restrict__ out) {
    const int lane = threadIdx.x & 63;
    const int w = __builtin_amdgcn_readfirstlane(threadIdx.x >> 6);
    const int wid = blockIdx.x * 4 + w;   // 0..1535
    const int strip = wid >> 3;           // 0..191
    const int mb = wid & 7;
    const int c0 = strip * 2;
    const int m = mb * 64 + lane;
    const float* orow = og + m * HD;
    float acc[2];
    acc[0] = 0.f; acc[1] = 0.f;
    for (int kb = 0; kb < HD; kb += 32) {
        float4 av[8];
        #pragma unroll
        for (int i = 0; i < 8; ++i) av[i] = ((const float4*)(orow + kb))[i];
        #pragma unroll
        for (int i = 0; i < 8; ++i) {
            const float* wr = Wo + (kb + i * 4) * CS + c0; // uniform -> s_load
            #pragma unroll
            for (int j = 0; j < 2; ++j) {
                acc[j] += av[i].x * wr[j];
                acc[j] += av[i].y * wr[CS + j];
                acc[j] += av[i].z * wr[2 * CS + j];
                acc[j] += av[i].w * wr[3 * CS + j];
            }
        }
    }
    #pragma unroll
    for (int j = 0; j < 2; ++j) out[m * CS + c0 + j] = acc[j] + bo[c0 + j];
}

extern "C" void kernel_launch(void* const* d_in, const int* in_sizes, int n_in,
                              void* d_out, int out_size, void* d_ws, size_t ws_size,
                              hipStream_t stream) {
    const float* a    = (const float*)d_in[0];
    const float* z    = (const float*)d_in[1];
    const float* g_a  = (const float*)d_in[2];
    const float* b_a  = (const float*)d_in[3];
    const float* g_z  = (const float*)d_in[4];
    const float* b_z  = (const float*)d_in[5];
    const float* Wz   = (const float*)d_in[6];
    const float* bz   = (const float*)d_in[7];
    const float* Wq   = (const float*)d_in[8];
    const float* Wk   = (const float*)d_in[9];
    const float* Wv   = (const float*)d_in[10];
    const float* Wg   = (const float*)d_in[11];
    const float* bg   = (const float*)d_in[12];
    const float* Wo   = (const float*)d_in[13];
    const float* bo   = (const float*)d_in[14];
    float* ws  = (float*)d_ws;
    float* out = (float*)d_out;

    float* an   = ws + OFF_AN;
    float* qt   = ws + OFF_QT;
    float* kt   = ws + OFF_KT;
    float* vt   = ws + OFF_VT;
    float* gt   = ws + OFF_GT;
    float* ogp  = ws + OFF_OG;
    float* wz2  = ws + OFF_WZ2;
    float* shp  = ws + OFF_SH;
    float* bhp  = ws + OFF_BH;
    float* bias = ws + OFF_BIAS;

    hipLaunchKernelGGL(ln_prep_kernel, dim3(257),    dim3(256), 0, stream,
                       a, g_a, b_a, an, g_z, b_z, Wz, bz, wz2, shp, bhp);
    hipLaunchKernelGGL(qp2_kernel,     dim3(4608),   dim3(256), 0, stream,
                       z, wz2, shp, bhp, bias,
                       Wq, Wk, Wv, Wg, bg, an, qt, kt, vt, gt);
    hipLaunchKernelGGL(attn_kernel,    dim3(64, 16), dim3(256), 0, stream,
                       qt, kt, vt, gt, bias, ogp);
    hipLaunchKernelGGL(out_gemm_kernel, dim3(384),   dim3(256), 0, stream,
                       Wo, bo, ogp, out);
}

// Round 6
// 333.810 us; speedup vs baseline: 1.2111x; 1.2111x over previous
//
#include <hip/hip_runtime.h>
#include <math.h>

#define N 512
#define CS 384
#define CZ 128
#define NH 16
#define DH 24
#define HD 384
#define NN (N*N)
#define EPS 1e-5f

// ws layout (float offsets)
#define OFF_AN   0          // a_n [N][CS]
#define OFF_QT   196608     // qT [H][N][D] (pre-scaled by 1/sqrt(24))
#define OFF_KT   393216     // kT [H][N][D]
#define OFF_VT   589824     // vT [H][N][D]
#define OFF_GT   786432     // gT [H][N][D] (sigmoid applied)
#define OFF_OG   983040     // o*g [N][HD]
#define OFF_WZ2  1179648    // g_z*Wz transposed [H][CZ]
#define OFF_SH   1181696    // [H]
#define OFF_BH   1181712    // [H]
#define OFF_BIAS 1181728    // pair bias [H][N][N]

// ---------------- fused: prep (block 256) + LayerNorm of a (blocks 0..255, 2 rows each) ----------------
__global__ void __launch_bounds__(256) ln_prep_kernel(const float* __restrict__ a, const float* __restrict__ g_a,
                                                      const float* __restrict__ b_a, float* __restrict__ an_out,
                                                      const float* __restrict__ g_z, const float* __restrict__ lnb_z,
                                                      const float* __restrict__ Wz, const float* __restrict__ bz,
                                                      float* __restrict__ wz2, float* __restrict__ sh,
                                                      float* __restrict__ bh) {
    __shared__ float ls[NH][17], lb[NH][17];   // prep block
    __shared__ float l1[4], l2[4];             // ln blocks
    const int t = threadIdx.x;
    if (blockIdx.x == 256) {
        for (int i = t; i < NH * CZ; i += 256) {
            int h = i >> 7, c = i & (CZ - 1);
            wz2[h * CZ + c] = g_z[c] * Wz[c * NH + h];
        }
        int h = t >> 4, seg = t & 15;
        float s = 0.f, b = 0.f;
        #pragma unroll
        for (int i = 0; i < 8; ++i) {
            int c = seg * 8 + i;
            float w = Wz[c * NH + h];
            s += g_z[c] * w;
            b += lnb_z[c] * w;
        }
        ls[h][seg] = s; lb[h][seg] = b;
        __syncthreads();
        if (t < NH) {
            float ss = 0.f, bb = 0.f;
            #pragma unroll
            for (int i = 0; i < 16; ++i) { ss += ls[t][i]; bb += lb[t][i]; }
            sh[t] = ss;
            bh[t] = bb + bz[t];
        }
        return;
    }
    const int half = t >> 7;
    const int tr = t & 127;
    const int r = blockIdx.x * 2 + half;
    const float* row = a + r * CS;
    float x0 = row[tr], x1 = row[tr + 128], x2 = row[tr + 256];
    float s1 = x0 + x1 + x2;
    float s2 = x0 * x0 + x1 * x1 + x2 * x2;
    #pragma unroll
    for (int m = 1; m < 64; m <<= 1) {
        s1 += __shfl_xor(s1, m, 64);
        s2 += __shfl_xor(s2, m, 64);
    }
    if ((t & 63) == 0) { l1[t >> 6] = s1; l2[t >> 6] = s2; }
    __syncthreads();
    s1 = l1[half * 2] + l1[half * 2 + 1];
    s2 = l2[half * 2] + l2[half * 2 + 1];
    float mu = s1 * (1.f / CS);
    float var = s2 * (1.f / CS) - mu * mu;
    float rs = rsqrtf(var + EPS);
    float* an = an_out + r * CS;
    an[tr]       = (x0 - mu) * rs * g_a[tr]       + b_a[tr];
    an[tr + 128] = (x1 - mu) * rs * g_a[tr + 128] + b_a[tr + 128];
    an[tr + 256] = (x2 - mu) * rs * g_a[tr + 256] + b_a[tr + 256];
}

// ---------------- qkvg v3: LDS-staged an-tile (coalesced), 4 cols/thread, 3072 waves ----------------
// Block: blockIdx.y = 64-row m-block (shared an tile), 4 waves = 4 strips of 4 cols.
// Per K-step: stage an[64][32] into LDS with coalesced float4 loads (16 lines/instr vs 64
// uncoalesced before); XOR slot swizzle (c^(r&7)) makes the per-lane row reads ~8-way (cheap).
__global__ void __launch_bounds__(256) qkvg_kernel(const float* __restrict__ Wq, const float* __restrict__ Wk,
                                                   const float* __restrict__ Wv, const float* __restrict__ Wg,
                                                   const float* __restrict__ bg, const float* __restrict__ an,
                                                   float* __restrict__ qt, float* __restrict__ kt,
                                                   float* __restrict__ vt, float* __restrict__ gt) {
    __shared__ float4 lan[64 * 8];   // 8 KB
    const int t = threadIdx.x;
    const int lane = t & 63;
    const int w = __builtin_amdgcn_readfirstlane(t >> 6);
    const int s = blockIdx.x * 4 + w;     // 0..383 strips
    const int n0 = s * 4;
    const int sel = n0 / HD;              // 0:q 1:k 2:v 3:g
    const int col = n0 - sel * HD;
    const float* Wm = (sel == 0) ? Wq : (sel == 1) ? Wk : (sel == 2) ? Wv : Wg;
    const int m0 = blockIdx.y * 64;
    const int m = m0 + lane;
    const float4* an4 = (const float4*)an;
    float acc[4];
    #pragma unroll
    for (int j = 0; j < 4; ++j) acc[j] = 0.f;
    for (int kb = 0; kb < CS; kb += 32) {
        __syncthreads();
        #pragma unroll
        for (int i = 0; i < 2; ++i) {
            const int idx = i * 256 + t;          // 0..511
            const int r = idx >> 3, c = idx & 7;
            lan[(r << 3) + (c ^ (r & 7))] = an4[(size_t)(m0 + r) * 96 + (kb >> 2) + c];
        }
        __syncthreads();
        float4 av[8];
        #pragma unroll
        for (int i = 0; i < 8; ++i) av[i] = lan[(lane << 3) + (i ^ (lane & 7))];
        #pragma unroll
        for (int i = 0; i < 8; ++i) {
            const float* wr = Wm + (kb + i * 4) * HD + col; // wave-uniform -> s_load
            #pragma unroll
            for (int j = 0; j < 4; ++j) {
                acc[j] += av[i].x * wr[j];
                acc[j] += av[i].y * wr[HD + j];
                acc[j] += av[i].z * wr[2 * HD + j];
                acc[j] += av[i].w * wr[3 * HD + j];
            }
        }
    }
    float* dst = (sel == 0) ? qt : (sel == 1) ? kt : (sel == 2) ? vt : gt;
    if (sel == 3) {
        #pragma unroll
        for (int j = 0; j < 4; ++j) acc[j] = 1.f / (1.f + __expf(-(acc[j] + bg[col + j])));
    } else if (sel == 0) {
        #pragma unroll
        for (int j = 0; j < 4; ++j) acc[j] *= 0.20412414523193153f; // 1/sqrt(24)
    }
    // 24%4==0 -> all 4 cols same head
    const int h = col / DH, d0 = col - h * DH;
    float* dp = dst + (h * N + m) * DH + d0;
    #pragma unroll
    for (int j = 0; j < 4; ++j) dp[j] = acc[j];
}

// ---------------- pair bias v4 (round-4 proven): 64-row tile, 4 threads/row, cheap-XOR LDS ----------------
__global__ void __launch_bounds__(256, 4) pairbias_kernel(const float* __restrict__ z,
                                                          const float* __restrict__ wz2,
                                                          const float* __restrict__ sh,
                                                          const float* __restrict__ bh,
                                                          float* __restrict__ bias) {
    __shared__ float4 lz[64 * 32];   // 32 KB
    const int t = threadIdx.x;
    const int l = t & 63;                                      // row within tile
    const int w = __builtin_amdgcn_readfirstlane(t >> 6);      // head group (wave-uniform)
    const int h0 = w * 4;
    const int row0 = blockIdx.x * 64;

    const float4* zsrc = (const float4*)(z + (size_t)row0 * CZ);
    #pragma unroll
    for (int i = 0; i < 8; ++i) {
        const int g4 = i * 256 + t;            // 0..2047
        float4 v = zsrc[g4];
        const int r = g4 >> 5, cc = g4 & 31;
        lz[r * 32 + (cc ^ (r & 31))] = v;
    }
    __syncthreads();

    const unsigned base = (unsigned)(l * 512 + ((l & 31) << 4));
    const char* lzb = (const char*)lz;
    float s1 = 0.f, s2 = 0.f;
    float dots[4];
    #pragma unroll
    for (int j = 0; j < 4; ++j) dots[j] = 0.f;
    #pragma unroll
    for (int cc = 0; cc < 32; ++cc) {
        float4 v = *(const float4*)(lzb + (base ^ (unsigned)(cc << 4)));
        s1 += v.x + v.y + v.z + v.w;
        s2 += v.x * v.x + v.y * v.y + v.z * v.z + v.w * v.w;
        #pragma unroll
        for (int j = 0; j < 4; ++j) {
            const float4 wv = ((const float4*)(wz2 + (h0 + j) * CZ))[cc]; // wave-uniform -> s_load
            dots[j] += v.x * wv.x + v.y * wv.y + v.z * wv.z + v.w * wv.w;
        }
    }
    const float mu = s1 * (1.f / CZ);
    const float var = s2 * (1.f / CZ) - mu * mu;
    const float rr = rsqrtf(var + EPS);
    const int row = row0 + l;
    #pragma unroll
    for (int j = 0; j < 4; ++j)
        bias[(h0 + j) * NN + row] = rr * (dots[j] - mu * sh[h0 + j]) + bh[h0 + j];
}

// ---------------- attn v2: flash-style with LDS-staged K/V tiles ----------------
// Block: head h, 8 q rows; 4 tiles of 128 k-rows. K,V staged coalesced (row = 6 float4
// exactly -> fully contiguous global reads), XOR slot swizzle for per-lane row reads.
// Online softmax (running m,l; rescale acc) so V is consumed tile-by-tile.
__global__ void __launch_bounds__(256, 4) attn_kernel(const float* __restrict__ qt, const float* __restrict__ kt,
                                                      const float* __restrict__ vt, const float* __restrict__ gt,
                                                      const float* __restrict__ bias, float* __restrict__ og) {
    __shared__ float4 lzK[128 * 8];   // 16 KB
    __shared__ float4 lzV[128 * 8];   // 16 KB
    const int t = threadIdx.x;
    const int lane = t & 63;
    const int w = __builtin_amdgcn_readfirstlane(t >> 6);
    const int qhalf = lane >> 5;     // 0/1
    const int klane = lane & 31;
    const int h = blockIdx.y;
    const int q = blockIdx.x * 8 + w * 2 + qhalf;
    const float* qT = qt + h * N * DH;
    const float4* kT4 = (const float4*)(kt + h * N * DH);
    const float4* vT4 = (const float4*)(vt + h * N * DH);
    const float* brow = bias + h * NN + q * N;

    float qv[DH];
    #pragma unroll
    for (int d6 = 0; d6 < 6; ++d6) {
        float4 t4 = ((const float4*)(qT + q * DH))[d6];
        qv[d6 * 4 + 0] = t4.x; qv[d6 * 4 + 1] = t4.y; qv[d6 * 4 + 2] = t4.z; qv[d6 * 4 + 3] = t4.w;
    }
    float m_run = -1e30f, l_run = 0.f;
    float acc[DH];
    #pragma unroll
    for (int d = 0; d < DH; ++d) acc[d] = 0.f;

    for (int tile = 0; tile < 4; ++tile) {
        __syncthreads();
        const int kt0 = tile * 128;
        #pragma unroll
        for (int i = 0; i < 3; ++i) {
            const int idx = i * 256 + t;       // 0..767 (= r*6+c, rows contiguous)
            const int r = idx / 6, c = idx - r * 6;
            const int slot = (r << 3) + (c ^ (r & 7));
            lzK[slot] = kT4[kt0 * 6 + idx];
            lzV[slot] = vT4[kt0 * 6 + idx];
        }
        __syncthreads();
        float sc[4];
        #pragma unroll
        for (int j = 0; j < 4; ++j) {
            const int kk = j * 32 + klane;
            const float4* kr = lzK + (kk << 3);
            const int x = kk & 7;
            float4 k0 = kr[0 ^ x], k1 = kr[1 ^ x], k2 = kr[2 ^ x],
                   k3 = kr[3 ^ x], k4 = kr[4 ^ x], k5 = kr[5 ^ x];
            float s = qv[0]*k0.x + qv[1]*k0.y + qv[2]*k0.z + qv[3]*k0.w
                    + qv[4]*k1.x + qv[5]*k1.y + qv[6]*k1.z + qv[7]*k1.w
                    + qv[8]*k2.x + qv[9]*k2.y + qv[10]*k2.z + qv[11]*k2.w
                    + qv[12]*k3.x + qv[13]*k3.y + qv[14]*k3.z + qv[15]*k3.w
                    + qv[16]*k4.x + qv[17]*k4.y + qv[18]*k4.z + qv[19]*k4.w
                    + qv[20]*k5.x + qv[21]*k5.y + qv[22]*k5.z + qv[23]*k5.w;
            sc[j] = s + brow[kt0 + kk];
        }
        float tm = fmaxf(fmaxf(sc[0], sc[1]), fmaxf(sc[2], sc[3]));
        #pragma unroll
        for (int m = 1; m < 32; m <<= 1) tm = fmaxf(tm, __shfl_xor(tm, m, 64));
        const float m_new = fmaxf(m_run, tm);
        const float scale = __expf(m_run - m_new);
        l_run *= scale;
        #pragma unroll
        for (int d = 0; d < DH; ++d) acc[d] *= scale;
        float p[4], ps = 0.f;
        #pragma unroll
        for (int j = 0; j < 4; ++j) { p[j] = __expf(sc[j] - m_new); ps += p[j]; }
        #pragma unroll
        for (int m = 1; m < 32; m <<= 1) ps += __shfl_xor(ps, m, 64);
        l_run += ps;
        m_run = m_new;
        #pragma unroll
        for (int j = 0; j < 4; ++j) {
            const int kk = j * 32 + klane;
            const float4* vr = lzV + (kk << 3);
            const int x = kk & 7;
            float4 v0 = vr[0 ^ x], v1 = vr[1 ^ x], v2 = vr[2 ^ x],
                   v3 = vr[3 ^ x], v4 = vr[4 ^ x], v5 = vr[5 ^ x];
            const float pj = p[j];
            acc[0] += pj*v0.x;  acc[1] += pj*v0.y;  acc[2] += pj*v0.z;  acc[3] += pj*v0.w;
            acc[4] += pj*v1.x;  acc[5] += pj*v1.y;  acc[6] += pj*v1.z;  acc[7] += pj*v1.w;
            acc[8] += pj*v2.x;  acc[9] += pj*v2.y;  acc[10] += pj*v2.z; acc[11] += pj*v2.w;
            acc[12] += pj*v3.x; acc[13] += pj*v3.y; acc[14] += pj*v3.z; acc[15] += pj*v3.w;
            acc[16] += pj*v4.x; acc[17] += pj*v4.y; acc[18] += pj*v4.z; acc[19] += pj*v4.w;
            acc[20] += pj*v5.x; acc[21] += pj*v5.y; acc[22] += pj*v5.z; acc[23] += pj*v5.w;
        }
    }
    #pragma unroll
    for (int m = 1; m < 32; m <<= 1) {
        #pragma unroll
        for (int d = 0; d < DH; ++d) acc[d] += __shfl_xor(acc[d], m, 64);
    }
    const float inv = 1.f / l_run;
    float o = 0.f;
    #pragma unroll
    for (int d = 0; d < DH; ++d) o = (klane == d) ? acc[d] : o;
    if (klane < DH) {
        float g = gt[h * N * DH + q * DH + klane];
        og[q * HD + h * DH + klane] = o * inv * g;
    }
}

// ---------------- out_gemm v3: LDS-staged og-tile, 2 cols/thread, 1536 waves ----------------
// Same staging pattern as qkvg v3 (og rows = 96 float4, identical geometry).
__global__ void __launch_bounds__(256) out_gemm_kernel(const float* __restrict__ Wo, const float* __restrict__ bo,
                                                       const float* __restrict__ og, float* __restrict__ out) {
    __shared__ float4 lo[64 * 8];    // 8 KB
    const int t = threadIdx.x;
    const int lane = t & 63;
    const int w = __builtin_amdgcn_readfirstlane(t >> 6);
    const int s = blockIdx.x * 4 + w;     // 0..191 strips of 2 cols
    const int c0 = s * 2;
    const int m0 = blockIdx.y * 64;
    const int m = m0 + lane;
    const float4* og4 = (const float4*)og;
    float acc[2];
    acc[0] = 0.f; acc[1] = 0.f;
    for (int kb = 0; kb < HD; kb += 32) {
        __syncthreads();
        #pragma unroll
        for (int i = 0; i < 2; ++i) {
            const int idx = i * 256 + t;          // 0..511
            const int r = idx >> 3, c = idx & 7;
            lo[(r << 3) + (c ^ (r & 7))] = og4[(size_t)(m0 + r) * 96 + (kb >> 2) + c];
        }
        __syncthreads();
        float4 av[8];
        #pragma unroll
        for (int i = 0; i < 8; ++i) av[i] = lo[(lane << 3) + (i ^ (lane & 7))];
        #pragma unroll
        for (int i = 0; i < 8; ++i) {
            const float* wr = Wo + (kb + i * 4) * CS + c0; // uniform -> s_load
            #pragma unroll
            for (int j = 0; j < 2; ++j) {
                acc[j] += av[i].x * wr[j];
                acc[j] += av[i].y * wr[CS + j];
                acc[j] += av[i].z * wr[2 * CS + j];
                acc[j] += av[i].w * wr[3 * CS + j];
            }
        }
    }
    #pragma unroll
    for (int j = 0; j < 2; ++j) out[m * CS + c0 + j] = acc[j] + bo[c0 + j];
}

extern "C" void kernel_launch(void* const* d_in, const int* in_sizes, int n_in,
                              void* d_out, int out_size, void* d_ws, size_t ws_size,
                              hipStream_t stream) {
    const float* a    = (const float*)d_in[0];
    const float* z    = (const float*)d_in[1];
    const float* g_a  = (const float*)d_in[2];
    const float* b_a  = (const float*)d_in[3];
    const float* g_z  = (const float*)d_in[4];
    const float* b_z  = (const float*)d_in[5];
    const float* Wz   = (const float*)d_in[6];
    const float* bz   = (const float*)d_in[7];
    const float* Wq   = (const float*)d_in[8];
    const float* Wk   = (const float*)d_in[9];
    const float* Wv   = (const float*)d_in[10];
    const float* Wg   = (const float*)d_in[11];
    const float* bg   = (const float*)d_in[12];
    const float* Wo   = (const float*)d_in[13];
    const float* bo   = (const float*)d_in[14];
    float* ws  = (float*)d_ws;
    float* out = (float*)d_out;

    float* an   = ws + OFF_AN;
    float* qt   = ws + OFF_QT;
    float* kt   = ws + OFF_KT;
    float* vt   = ws + OFF_VT;
    float* gt   = ws + OFF_GT;
    float* ogp  = ws + OFF_OG;
    float* wz2  = ws + OFF_WZ2;
    float* shp  = ws + OFF_SH;
    float* bhp  = ws + OFF_BH;
    float* bias = ws + OFF_BIAS;

    hipLaunchKernelGGL(ln_prep_kernel, dim3(257),    dim3(256), 0, stream,
                       a, g_a, b_a, an, g_z, b_z, Wz, bz, wz2, shp, bhp);
    hipLaunchKernelGGL(qkvg_kernel,    dim3(96, 8),  dim3(256), 0, stream,
                       Wq, Wk, Wv, Wg, bg, an, qt, kt, vt, gt);
    hipLaunchKernelGGL(pairbias_kernel, dim3(4096),  dim3(256), 0, stream,
                       z, wz2, shp, bhp, bias);
    hipLaunchKernelGGL(attn_kernel,    dim3(64, 16), dim3(256), 0, stream,
                       qt, kt, vt, gt, bias, ogp);
    hipLaunchKernelGGL(out_gemm_kernel, dim3(48, 8), dim3(256), 0, stream,
                       Wo, bo, ogp, out);
}